// Round 1
// baseline (152.366 us; speedup 1.0000x reference)
//
#include <hip/hip_runtime.h>
#include <cstdint>
#include <cstddef>

// 20-qubit statevector sim, 3 layers of [U3 x20 + CU3 ring (0,1)..(19,0)].
// 6 dispatches: 6 tile passes (2 per layer); mean-subtract fused into the
// last pass via fence-free arrive-and-spin (all 512 blocks co-resident:
// LDS 38.2KB -> 4 blk/CU, launch_bounds(256,2) -> >=2 blk/CU regs).
// Only the 4-byte accum scalar crosses blocks after the spin (device-scope
// atomic) -- no wbl2/inv data fences needed (those cost ~100us/barrier,
// R5/R6). Dispatch boundaries provide psi coherence (~10us each).
//
// Pass S1(k): U3 q0..q10 + CU3 (0,1)..(9,10); tile bits 0..10 = q0..q10,
//   block bits 11..19 = q11..q19.
// Pass S2(k): U3 q11..q19 + CU3 (10,11)..(19,0); tile = (q10,q11..q19,q0),
//   block = (q1..q9).
// Within a pass: 5 phases, register window always tile bits (0,1,2);
// between phases the tile rotates down by 2 (L' = (L>>2)|((L&3)<<9)),
// LDS double-buffered, 1 sync per rotation, all LDS ops b128.
// After 4 rotations the final register layout is rotated by 8; global
// stores map to the next pass's layout (16B float4 runs; next-pass reads
// are contiguous 16KB tiles). All layout math verified in R5/R6 (passed).
// Final pass: x = (0.8*tanh(0.1*2^19*|a|^2))^0.3 in registers, block sum
// -> atomicAdd(accum); arrive counter at accum[1]; t0 spins until all 512
// arrived, broadcasts mean via LDS; scattered bit-reversed store of
// (x - mean) to out.

#define NB 512
#define NT 256
#define PHYS(L) ((L) + 2u * ((L) >> 4))

__device__ __forceinline__ float2 cmadd2(float2 m0, float2 a0, float2 m1, float2 a1) {
  float2 r;
  r.x = m0.x * a0.x - m0.y * a0.y + m1.x * a1.x - m1.y * a1.y;
  r.y = m0.x * a0.y + m0.y * a0.x + m1.x * a1.y + m1.y * a1.x;
  return r;
}

template <int BIT>
__device__ __forceinline__ void applyU3(float2* v, const float2* m) {
  float2 m00 = m[0], m01 = m[1], m10 = m[2], m11 = m[3];
#pragma unroll
  for (int j = 0; j < 8; j++)
    if (!((j >> BIT) & 1)) {
      int j1 = j | (1 << BIT);
      float2 a0 = v[j], a1 = v[j1];
      v[j] = cmadd2(m00, a0, m01, a1);
      v[j1] = cmadd2(m10, a0, m11, a1);
    }
}

template <int C, int T>
__device__ __forceinline__ void applyCU3(float2* v, const float2* m) {
  float2 u00 = m[0], u01 = m[1], u10 = m[2], u11 = m[3];
#pragma unroll
  for (int j = 0; j < 8; j++)
    if (((j >> C) & 1) && !((j >> T) & 1)) {
      int j1 = j | (1 << T);
      float2 a0 = v[j], a1 = v[j1];
      v[j] = cmadd2(u00, a0, u01, a1);
      v[j1] = cmadd2(u10, a0, u11, a1);
    }
}

// One phase on window bits (0,1,2). U*/C* = within-layer gate ids (-1 = skip).
// MU: U3 qubit q at [4q]; MC: CU3 control c at [4c].
template <int U0, int U1, int U2, int C01, int C12>
__device__ __forceinline__ void phase(float2* v, const float2* MU, const float2* MC) {
  if (U0 >= 0) applyU3<0>(v, MU + 4 * (U0 < 0 ? 0 : U0));
  if (U1 >= 0) applyU3<1>(v, MU + 4 * (U1 < 0 ? 0 : U1));
  if (U2 >= 0) applyU3<2>(v, MU + 4 * (U2 < 0 ? 0 : U2));
  if (C01 >= 0) applyCU3<0, 1>(v, MC + 4 * (C01 < 0 ? 0 : C01));
  if (C12 >= 0) applyCU3<1, 2>(v, MC + 4 * (C12 < 0 ? 0 : C12));
}

// store v (layout L=8t+m) rotated: L' = (L>>2)|((L&3)<<9) = 2t+(m>>2)+(m&3)<<9
__device__ __forceinline__ void rot_store(float2* lds, unsigned t, const float2* v) {
#pragma unroll
  for (int q = 0; q < 4; q++) {
    unsigned Lp = 2u * t + 512u * q;
    *(float4*)&lds[PHYS(Lp)] = make_float4(v[q].x, v[q].y, v[q + 4].x, v[q + 4].y);
  }
}

__device__ __forceinline__ void rot_load(const float2* lds, unsigned t, float2* v) {
  const float4* p = (const float4*)&lds[PHYS(8u * t)];
#pragma unroll
  for (int i = 0; i < 4; i++) {
    float4 f = p[i];
    v[2 * i] = make_float2(f.x, f.y);
    v[2 * i + 1] = make_float2(f.z, f.w);
  }
}

__device__ __forceinline__ float xval(float2 a) {
  float p = a.x * a.x + a.y * a.y;
  return powf(0.8f * tanhf(52428.8f * p), 0.3f);
}

__device__ __forceinline__ void mat_from(const float* s, float2* m) {
  float st, ct, sl, cl, sp, cp, spl, cpl;
  sincosf(0.5f * s[0], &st, &ct);
  sincosf(s[2], &sl, &cl);
  sincosf(s[1], &sp, &cp);
  sincosf(s[1] + s[2], &spl, &cpl);
  m[0] = make_float2(ct, 0.f);
  m[1] = make_float2(-cl * st, -sl * st);
  m[2] = make_float2(cp * st, sp * st);
  m[3] = make_float2(cpl * ct, spl * ct);
}

// TYPE 0 = S1, 1 = S2; INIT synthesizes |0..0>; FINAL does readout.
template <int TYPE, int INIT, int FINAL>
__global__ __launch_bounds__(NT, 2) void pass_k(const float* __restrict__ u3p,
                                                const float* __restrict__ cu3p, int k,
                                                const float2* __restrict__ in,
                                                float2* __restrict__ outPsi,
                                                float* __restrict__ accum,
                                                float* __restrict__ out) {
  __shared__ float2 A[2304], B[2304];  // PHYS(2047)=2301
  __shared__ float2 M[160];            // U3 q at [4q]; CU3 c at [80+4c]
  __shared__ float red[4];
  unsigned t = threadIdx.x, b = blockIdx.x;

  // start psi loads first so they overlap the sincos below
  float2 v[8];
  if (INIT) {
#pragma unroll
    for (int j = 0; j < 8; j++) v[j] = make_float2(0.f, 0.f);
    if (b == 0 && t == 0) {
      v[0] = make_float2(1.f, 0.f);
      accum[0] = 0.f;                       // running sum of x
      *(unsigned*)(accum + 1) = 0u;         // arrive counter for final pass
    }
  } else {
    const float4* in4 = (const float4*)in + ((size_t)b << 10) + 4u * t;
#pragma unroll
    for (int i = 0; i < 4; i++) {
      float4 f = in4[i];
      v[2 * i] = make_float2(f.x, f.y);
      v[2 * i + 1] = make_float2(f.z, f.w);
    }
  }

  // this layer's 40 gate matrices
  if (t < 20) mat_from(u3p + (k * 20 + t) * 3, M + 4 * t);
  else if (t >= 64 && t < 84) mat_from(cu3p + (k * 20 + (t - 64)) * 3, M + 80 + 4 * (t - 64));
  __syncthreads();

  const float2* MU = M;
  const float2* MC = M + 80;
  if (TYPE == 0) phase<0, 1, 2, 0, 1>(v, MU, MC);      else phase<-1, 11, 12, 10, 11>(v, MU, MC);
  rot_store(A, t, v); __syncthreads(); rot_load(A, t, v);
  if (TYPE == 0) phase<-1, 3, 4, 2, 3>(v, MU, MC);     else phase<-1, 13, 14, 12, 13>(v, MU, MC);
  rot_store(B, t, v); __syncthreads(); rot_load(B, t, v);
  if (TYPE == 0) phase<-1, 5, 6, 4, 5>(v, MU, MC);     else phase<-1, 15, 16, 14, 15>(v, MU, MC);
  rot_store(A, t, v); __syncthreads(); rot_load(A, t, v);
  if (TYPE == 0) phase<-1, 7, 8, 6, 7>(v, MU, MC);     else phase<-1, 17, 18, 16, 17>(v, MU, MC);
  rot_store(B, t, v); __syncthreads(); rot_load(B, t, v);
  if (TYPE == 0) phase<-1, 9, 10, 8, 9>(v, MU, MC);    else phase<-1, 19, -1, 18, 19>(v, MU, MC);

  // final register layout (rot by 8): m=(w8,w9,w10), t=(w0..w7) of this
  // pass's chain. Next-pass global index (both directions, by symmetry):
  // f4 = blk + 512*t0 + 1024*(t>>1) + 2^17*m0 + 2^18*m1  (pair over m2)
  if (!FINAL) {
    float4* o4 = (float4*)outPsi;
    unsigned base = b + ((t & 1u) << 9) + ((t >> 1) << 10);
    o4[base] = make_float4(v[0].x, v[0].y, v[4].x, v[4].y);
    o4[base + (1u << 17)] = make_float4(v[1].x, v[1].y, v[5].x, v[5].y);
    o4[base + (1u << 18)] = make_float4(v[2].x, v[2].y, v[6].x, v[6].y);
    o4[base + (3u << 17)] = make_float4(v[3].x, v[3].y, v[7].x, v[7].y);
  } else {
    // S2(2) end: m=(q18,q19,q0), t=(q10..q17), blk=(q1..q9).
    // Reference R (bit 19-q): R = m1 + 2*m0 + 4*rev8(t) + 1024*rev9(b) + 2^19*m2
    float xv[8];
    float s = 0.f;
#pragma unroll
    for (int m = 0; m < 8; m++) { xv[m] = xval(v[m]); s += xv[m]; }
#pragma unroll
    for (int o = 32; o > 0; o >>= 1) s += __shfl_down(s, o);
    if ((t & 63u) == 0) red[t >> 6] = s;
    __syncthreads();
    if (t == 0) {
      unsigned* cnt = (unsigned*)(accum + 1);
      float tot = red[0] + red[1] + red[2] + red[3];
      // device-scope add of this block's partial; force the returning form
      // and wait for the ack so the add is globally performed before arrive.
      float oldv = __hip_atomic_fetch_add(accum, tot, __ATOMIC_RELAXED,
                                          __HIP_MEMORY_SCOPE_AGENT);
      asm volatile("" ::"v"(oldv));
      asm volatile("s_waitcnt vmcnt(0)" ::: "memory");
      __hip_atomic_fetch_add(cnt, 1u, __ATOMIC_RELAXED, __HIP_MEMORY_SCOPE_AGENT);
      unsigned c;
      do {
        __builtin_amdgcn_s_sleep(8);
        c = __hip_atomic_load(cnt, __ATOMIC_RELAXED, __HIP_MEMORY_SCOPE_AGENT);
      } while (c < NB);
      red[0] = __hip_atomic_load(accum, __ATOMIC_RELAXED, __HIP_MEMORY_SCOPE_AGENT);
    }
    __syncthreads();
    float mean = red[0] * (1.f / 1048576.f);
    float4* o4 = (float4*)out;
    unsigned base = (__brev(t) >> 24) + ((__brev(b) >> 23) << 8);
    o4[base] = make_float4(xv[0] - mean, xv[2] - mean, xv[1] - mean, xv[3] - mean);
    o4[base + (1u << 17)] =
        make_float4(xv[4] - mean, xv[6] - mean, xv[5] - mean, xv[7] - mean);
  }
}

extern "C" void kernel_launch(void* const* d_in, const int* in_sizes, int n_in,
                              void* d_out, int out_size, void* d_ws, size_t ws_size,
                              hipStream_t stream) {
  const float* u3p = (const float*)d_in[0];
  const float* cu3p = (const float*)d_in[1];
  float* out = (float*)d_out;

  char* ws = (char*)d_ws;
  float2* psiA = (float2*)ws;                              // 8 MB
  float2* psiB = (float2*)(ws + (size_t)8 * 1024 * 1024);  // 8 MB
  float* accum = (float*)(ws + (size_t)16 * 1024 * 1024);  // [0]=sum, [1]=cnt

  pass_k<0, 1, 0><<<NB, NT, 0, stream>>>(u3p, cu3p, 0, nullptr, psiB, accum, out);
  pass_k<1, 0, 0><<<NB, NT, 0, stream>>>(u3p, cu3p, 0, psiB, psiA, accum, out);
  pass_k<0, 0, 0><<<NB, NT, 0, stream>>>(u3p, cu3p, 1, psiA, psiB, accum, out);
  pass_k<1, 0, 0><<<NB, NT, 0, stream>>>(u3p, cu3p, 1, psiB, psiA, accum, out);
  pass_k<0, 0, 0><<<NB, NT, 0, stream>>>(u3p, cu3p, 2, psiA, psiB, accum, out);
  pass_k<1, 0, 1><<<NB, NT, 0, stream>>>(u3p, cu3p, 2, psiB, nullptr, accum, out);
}

// Round 2
// 147.926 us; speedup vs baseline: 1.0300x; 1.0300x over previous
//
#include <hip/hip_runtime.h>
#include <cstdint>
#include <cstddef>

// 20-qubit statevector sim, 3 layers of [U3 x20 + CU3 ring (0,1)..(19,0)].
// 7 dispatches: 6 tile passes (2 per layer) + tiny mean-subtract kernel.
// (R1 post-mortem: fused spin-barrier readout cost +17us — the global
// arrive-and-spin serializes the store tail behind the slowest block.
// Reverted to fin_k dispatch.)
//
// R2 restructure: within a pass, tile bits are (w0..w2)=register window,
// (w3..w8)=lane bits, (w9,w10)=wave bits. Gates on bits 0..8 are WAVE-LOCAL:
// window gates in registers, lane-bit gates via ds_swizzle xor (masks 1..16)
// and __shfl_xor 32. Zero barriers for the first 17 gates. Then ONE LDS
// rotation by 8 (XOR-swizzled addresses, <=4-way conflicts) brings bits
// (8,9,10) into the window for the last 3-4 gates. Barriers/pass: 5 -> 2.
//
// Pass S1(k): U3 q0..q10 + CU3 (0,1)..(9,10); tile bits 0..10 = q0..q10,
//   block bits 11..19 = q11..q19.
// Pass S2(k): U3 q11..q19 + CU3 (10,11)..(19,0); tile = (q10,q11..q19,q0),
//   block = (q1..q9).
// Initial register layout L=8t+j and final layout (rot by 8) are identical
// to the R0 kernel, so the verified global load/store mappings are reused
// verbatim: stores scatter 16B runs into the next pass's layout; next-pass
// reads are contiguous 16KB tiles.
// Final pass: x = (0.8*tanh(0.1*2^19*|a|^2))^0.3 in registers, scattered
// bit-reversed store to out (no mean), block sum -> atomicAdd(accum);
// fin kernel subtracts mean.

#define NB 512
#define NT 256

__device__ __forceinline__ float2 cmadd2(float2 m0, float2 a0, float2 m1, float2 a1) {
  float2 r;
  r.x = m0.x * a0.x - m0.y * a0.y + m1.x * a1.x - m1.y * a1.y;
  r.y = m0.x * a0.y + m0.y * a0.x + m1.x * a1.y + m1.y * a1.x;
  return r;
}

// intra-wave xor exchange of a float2 (MASK in {1,2,4,8,16,32})
template <int MASK>
__device__ __forceinline__ float2 lanexor(float2 a) {
  if constexpr (MASK == 32) {
    return make_float2(__shfl_xor(a.x, 32), __shfl_xor(a.y, 32));
  } else {
    constexpr int pat = (MASK << 10) | 0x1F;  // BitMode: src = lane ^ MASK
    return make_float2(
        __int_as_float(__builtin_amdgcn_ds_swizzle(__float_as_int(a.x), pat)),
        __int_as_float(__builtin_amdgcn_ds_swizzle(__float_as_int(a.y), pat)));
  }
}

template <int BIT>
__device__ __forceinline__ void applyU3(float2* v, const float2* m) {
  float2 m00 = m[0], m01 = m[1], m10 = m[2], m11 = m[3];
#pragma unroll
  for (int j = 0; j < 8; j++)
    if (!((j >> BIT) & 1)) {
      int j1 = j | (1 << BIT);
      float2 a0 = v[j], a1 = v[j1];
      v[j] = cmadd2(m00, a0, m01, a1);
      v[j1] = cmadd2(m10, a0, m11, a1);
    }
}

template <int C, int T>
__device__ __forceinline__ void applyCU3(float2* v, const float2* m) {
  float2 u00 = m[0], u01 = m[1], u10 = m[2], u11 = m[3];
#pragma unroll
  for (int j = 0; j < 8; j++)
    if (((j >> C) & 1) && !((j >> T) & 1)) {
      int j1 = j | (1 << T);
      float2 a0 = v[j], a1 = v[j1];
      v[j] = cmadd2(u00, a0, u01, a1);
      v[j1] = cmadd2(u10, a0, u11, a1);
    }
}

// U3 on a lane bit: every amp pairs with the partner lane (lane ^ MASK).
// self-bit=0: v' = m00*self + m01*partner ; self-bit=1: v' = m11*self + m10*partner
template <int MASK>
__device__ __forceinline__ void applyU3L(float2* v, const float2* m, unsigned lane) {
  bool hi = (lane & MASK) != 0;
  float2 s0 = hi ? m[3] : m[0];
  float2 s1 = hi ? m[2] : m[1];
#pragma unroll
  for (int j = 0; j < 8; j++) {
    float2 p = lanexor<MASK>(v[j]);
    v[j] = cmadd2(s0, v[j], s1, p);
  }
}

// CU3 with window-bit control C, lane-bit target MASK: active regs j have bit C set.
template <int C, int MASK>
__device__ __forceinline__ void applyCU3WL(float2* v, const float2* m, unsigned lane) {
  bool hi = (lane & MASK) != 0;
  float2 s0 = hi ? m[3] : m[0];
  float2 s1 = hi ? m[2] : m[1];
#pragma unroll
  for (int j = 0; j < 8; j++)
    if ((j >> C) & 1) {
      float2 p = lanexor<MASK>(v[j]);
      v[j] = cmadd2(s0, v[j], s1, p);
    }
}

// CU3 with lane-bit control CMASK, lane-bit target TMASK: lanes with control=0
// keep their amps (predicated select; partners of active lanes are active).
template <int CMASK, int TMASK>
__device__ __forceinline__ void applyCU3LL(float2* v, const float2* m, unsigned lane) {
  bool act = (lane & CMASK) != 0;
  bool hi = (lane & TMASK) != 0;
  float2 s0 = hi ? m[3] : m[0];
  float2 s1 = hi ? m[2] : m[1];
#pragma unroll
  for (int j = 0; j < 8; j++) {
    float2 p = lanexor<TMASK>(v[j]);
    float2 nv = cmadd2(s0, v[j], s1, p);
    v[j].x = act ? nv.x : v[j].x;
    v[j].y = act ? nv.y : v[j].y;
  }
}

__device__ __forceinline__ float xval(float2 a) {
  float p = a.x * a.x + a.y * a.y;
  return powf(0.8f * tanhf(52428.8f * p), 0.3f);
}

__device__ __forceinline__ void mat_from(const float* s, float2* m) {
  float st, ct, sl, cl, sp, cp, spl, cpl;
  sincosf(0.5f * s[0], &st, &ct);
  sincosf(s[2], &sl, &cl);
  sincosf(s[1], &sp, &cp);
  sincosf(s[1] + s[2], &spl, &cpl);
  m[0] = make_float2(ct, 0.f);
  m[1] = make_float2(-cl * st, -sl * st);
  m[2] = make_float2(cp * st, sp * st);
  m[3] = make_float2(cpl * ct, spl * ct);
}

// TYPE 0 = S1, 1 = S2; INIT synthesizes |0..0>; FINAL does readout.
template <int TYPE, int INIT, int FINAL>
__global__ __launch_bounds__(NT) void pass_k(const float* __restrict__ u3p,
                                             const float* __restrict__ cu3p, int k,
                                             const float2* __restrict__ in,
                                             float2* __restrict__ outPsi,
                                             float* __restrict__ accum,
                                             float* __restrict__ out) {
  __shared__ float2 A[2048];  // rotation buffer, XOR-swizzled addressing
  __shared__ float2 M[160];   // U3 q at [4q]; CU3 c at [80+4c]
  __shared__ float red[4];
  unsigned t = threadIdx.x, b = blockIdx.x;
  unsigned lane = t & 63u;

  // start psi loads first so they overlap the sincos below
  float2 v[8];
  if (INIT) {
#pragma unroll
    for (int j = 0; j < 8; j++) v[j] = make_float2(0.f, 0.f);
    if (b == 0 && t == 0) { v[0] = make_float2(1.f, 0.f); *accum = 0.f; }
  } else {
    const float4* in4 = (const float4*)in + ((size_t)b << 10) + 4u * t;
#pragma unroll
    for (int i = 0; i < 4; i++) {
      float4 f = in4[i];
      v[2 * i] = make_float2(f.x, f.y);
      v[2 * i + 1] = make_float2(f.z, f.w);
    }
  }

  // this layer's 40 gate matrices
  if (t < 20) mat_from(u3p + (k * 20 + t) * 3, M + 4 * t);
  else if (t >= 64 && t < 84) mat_from(cu3p + (k * 20 + (t - 64)) * 3, M + 80 + 4 * (t - 64));
  __syncthreads();

  const float2* MU = M;
  const float2* MC = M + 80;
  constexpr int UB = TYPE ? 11 : 1;  // U3 id at tile bit 1
  constexpr int CB = TYPE ? 10 : 0;  // CU3 id at link (0,1)

  // ---- stage 1: 17 (S1) / 16 (S2) gates, wave-local, no barriers ----
  if (TYPE == 0) applyU3<0>(v, MU + 0);
  applyU3<1>(v, MU + 4 * UB);
  applyCU3<0, 1>(v, MC + 4 * CB);
  applyU3<2>(v, MU + 4 * (UB + 1));
  applyCU3<1, 2>(v, MC + 4 * (CB + 1));
  applyU3L<1>(v, MU + 4 * (UB + 2), lane);
  applyCU3WL<2, 1>(v, MC + 4 * (CB + 2), lane);
  applyU3L<2>(v, MU + 4 * (UB + 3), lane);
  applyCU3LL<1, 2>(v, MC + 4 * (CB + 3), lane);
  applyU3L<4>(v, MU + 4 * (UB + 4), lane);
  applyCU3LL<2, 4>(v, MC + 4 * (CB + 4), lane);
  applyU3L<8>(v, MU + 4 * (UB + 5), lane);
  applyCU3LL<4, 8>(v, MC + 4 * (CB + 5), lane);
  applyU3L<16>(v, MU + 4 * (UB + 6), lane);
  applyCU3LL<8, 16>(v, MC + 4 * (CB + 6), lane);
  applyU3L<32>(v, MU + 4 * (UB + 7), lane);
  applyCU3LL<16, 32>(v, MC + 4 * (CB + 7), lane);

  // ---- one LDS rotation by 8: L' = (L>>8)|((L&255)<<3) ----
  // store addr (float2 idx): L' = (t>>5) + 64*(t&31) + 8j; XOR-swizzle low
  // 4 bits with (idx>>6)&15 to break the 64-stride bank pattern (<=4-way).
  {
    unsigned baseS = (t >> 5) + 64u * (t & 31u);
#pragma unroll
    for (int j = 0; j < 8; j++) {
      unsigned Lp = baseS + 8u * j;
      A[Lp ^ ((Lp >> 6) & 15u)] = v[j];
    }
    __syncthreads();
#pragma unroll
    for (int j = 0; j < 8; j++) {
      unsigned Lr = 8u * t + j;
      v[j] = A[Lr ^ ((Lr >> 6) & 15u)];
    }
  }

  // ---- stage 2: window = old tile bits (8,9,10) ----
  applyU3<1>(v, MU + 4 * (TYPE ? 19 : 9));
  applyCU3<0, 1>(v, MC + 4 * (TYPE ? 18 : 8));
  if (TYPE == 0) applyU3<2>(v, MU + 4 * 10);
  applyCU3<1, 2>(v, MC + 4 * (TYPE ? 19 : 9));

  // final register layout (rot by 8): m=(w8,w9,w10), t=(w0..w7) of this
  // pass's chain. Next-pass global index (both directions, by symmetry):
  // f4 = blk + 512*t0 + 1024*(t>>1) + 2^17*m0 + 2^18*m1  (pair over m2)
  if (!FINAL) {
    float4* o4 = (float4*)outPsi;
    unsigned base = b + ((t & 1u) << 9) + ((t >> 1) << 10);
    o4[base] = make_float4(v[0].x, v[0].y, v[4].x, v[4].y);
    o4[base + (1u << 17)] = make_float4(v[1].x, v[1].y, v[5].x, v[5].y);
    o4[base + (1u << 18)] = make_float4(v[2].x, v[2].y, v[6].x, v[6].y);
    o4[base + (3u << 17)] = make_float4(v[3].x, v[3].y, v[7].x, v[7].y);
  } else {
    // S2(2) end: m=(q18,q19,q0), t=(q10..q17), blk=(q1..q9).
    // Reference R (bit 19-q): R = m1 + 2*m0 + 4*rev8(t) + 1024*rev9(b) + 2^19*m2
    float xv[8];
    float s = 0.f;
#pragma unroll
    for (int m = 0; m < 8; m++) { xv[m] = xval(v[m]); s += xv[m]; }
    float4* o4 = (float4*)out;
    unsigned base = (__brev(t) >> 24) + ((__brev(b) >> 23) << 8);
    o4[base] = make_float4(xv[0], xv[2], xv[1], xv[3]);
    o4[base + (1u << 17)] = make_float4(xv[4], xv[6], xv[5], xv[7]);
#pragma unroll
    for (int o = 32; o > 0; o >>= 1) s += __shfl_down(s, o);
    if ((t & 63u) == 0) red[t >> 6] = s;
    __syncthreads();
    if (t == 0) atomicAdd(accum, red[0] + red[1] + red[2] + red[3]);
  }
}

__global__ void fin_k(float* __restrict__ out, const float* __restrict__ accum) {
  unsigned i = blockIdx.x * blockDim.x + threadIdx.x;
  float mean = *accum * (1.f / 1048576.f);
  float4* o4 = (float4*)out;
  float4 x = o4[i];
  x.x -= mean; x.y -= mean; x.z -= mean; x.w -= mean;
  o4[i] = x;
}

extern "C" void kernel_launch(void* const* d_in, const int* in_sizes, int n_in,
                              void* d_out, int out_size, void* d_ws, size_t ws_size,
                              hipStream_t stream) {
  const float* u3p = (const float*)d_in[0];
  const float* cu3p = (const float*)d_in[1];
  float* out = (float*)d_out;

  char* ws = (char*)d_ws;
  float2* psiA = (float2*)ws;                              // 8 MB
  float2* psiB = (float2*)(ws + (size_t)8 * 1024 * 1024);  // 8 MB
  float* accum = (float*)(ws + (size_t)16 * 1024 * 1024);

  pass_k<0, 1, 0><<<NB, NT, 0, stream>>>(u3p, cu3p, 0, nullptr, psiB, accum, out);
  pass_k<1, 0, 0><<<NB, NT, 0, stream>>>(u3p, cu3p, 0, psiB, psiA, accum, out);
  pass_k<0, 0, 0><<<NB, NT, 0, stream>>>(u3p, cu3p, 1, psiA, psiB, accum, out);
  pass_k<1, 0, 0><<<NB, NT, 0, stream>>>(u3p, cu3p, 1, psiB, psiA, accum, out);
  pass_k<0, 0, 0><<<NB, NT, 0, stream>>>(u3p, cu3p, 2, psiA, psiB, accum, out);
  pass_k<1, 0, 1><<<NB, NT, 0, stream>>>(u3p, cu3p, 2, psiB, nullptr, accum, out);
  fin_k<<<1024, 256, 0, stream>>>(out, accum);
}

// Round 3
// 135.409 us; speedup vs baseline: 1.1252x; 1.0924x over previous
//
#include <hip/hip_runtime.h>
#include <cstdint>
#include <cstddef>

// 20-qubit statevector sim, 3 layers of [U3 x20 + CU3 ring (0,1)..(19,0)].
// 7 dispatches: 6 tile passes (2 per layer) + tiny mean-subtract kernel.
//
// R3: occupancy restructure. R2 showed barrier count isn't the bottleneck
// (2-barrier swizzle version was SLOWER); passes are latency-stall-bound at
// 2 waves/SIMD. This version: NT=512, v[4] (4 amps/thread) -> 4096 waves =
// 4 waves/SIMD, 16 waves/CU, still 512 blocks (full machine), same 11-bit
// tiles. Window = bits (0,1); rotate-by-1 per phase, 10 phases/pass,
// 9 rotations (double-buffered, XOR-bank-swizzle SW(i)=i^((i>>3)&1),
// conflict-free per 8-lane group for both store and load patterns).
// U3+CU3 FUSED per phase: W0 = U3(target) for control=0, W1 = u_c*U3 for
// control=1, precomputed in LDS matrix stage -> 8 cmadd2/phase vs 12.
//
// Pass S1(k): U3 q0..q10 + CU3 (0,1)..(9,10); tile bits 0..10 = q0..q10,
//   block bits = q11..q19.  Phase p (window = tile bits (p,p+1)):
//   p=0: U0 standalone + F(U1,C01); p>=1: F(U_{p+1}, C_{p,p+1}).
// Pass S2(k): tile = (q10,q11..q19,q0), block = q1..q9.
//   p=0..8: F(U_{11+p}, C_{10+p,11+p}); p=9: raw C(19,0) (U3 q0 done in S1).
// After 9 rotations: regs j=(tile bit9, bit10), t = tile bits 0..8.
// Inter-pass store (derived; bit-identical to the R0-verified formula):
//   f4 = b + t0*2^9 + (t>>1)*2^10 + j0*2^18, f4 content pairs over j1.
//   Same formula both directions (bit-role swap is symmetric).
// Final readout: R = j0 + 2*rev9(t) + 1024*rev9(b) + 2^19*j1 ->
//   float2 (x0,x1) at f2 idx rev9(t)+512*rev9(b), (x2,x3) at +2^18.
//   Block sum -> atomicAdd(accum); fin_k subtracts mean.

#define NB 512
#define NT 512
#define SW(i) ((i) ^ (((i) >> 3) & 1u))

__device__ __forceinline__ float2 cmadd2(float2 m0, float2 a0, float2 m1, float2 a1) {
  float2 r;
  r.x = m0.x * a0.x - m0.y * a0.y + m1.x * a1.x - m1.y * a1.y;
  r.y = m0.x * a0.y + m0.y * a0.x + m1.x * a1.y + m1.y * a1.x;
  return r;
}
__device__ __forceinline__ float2 cmul(float2 a, float2 b) {
  return make_float2(a.x * b.x - a.y * b.y, a.x * b.y + a.y * b.x);
}
__device__ __forceinline__ float2 cadd(float2 a, float2 b) {
  return make_float2(a.x + b.x, a.y + b.y);
}

// U3 on window bit0: pairs (0,1),(2,3)
__device__ __forceinline__ void applyU3b0(float2* v, const float2* m) {
  float2 m00 = m[0], m01 = m[1], m10 = m[2], m11 = m[3];
  float2 a0 = v[0], a1 = v[1];
  v[0] = cmadd2(m00, a0, m01, a1); v[1] = cmadd2(m10, a0, m11, a1);
  a0 = v[2]; a1 = v[3];
  v[2] = cmadd2(m00, a0, m01, a1); v[3] = cmadd2(m10, a0, m11, a1);
}
// fused [U3 on bit1, then CU3(ctrl=bit0,tgt=bit1)]: W0 acts on (v0,v2), W1 on (v1,v3)
__device__ __forceinline__ void applyF(float2* v, const float2* W0, const float2* W1) {
  float2 a0 = v[0], a1 = v[2];
  v[0] = cmadd2(W0[0], a0, W0[1], a1); v[2] = cmadd2(W0[2], a0, W0[3], a1);
  a0 = v[1]; a1 = v[3];
  v[1] = cmadd2(W1[0], a0, W1[1], a1); v[3] = cmadd2(W1[2], a0, W1[3], a1);
}
// raw CU3 ctrl bit0, tgt bit1: only (v1,v3)
__device__ __forceinline__ void applyC(float2* v, const float2* u) {
  float2 a0 = v[1], a1 = v[3];
  v[1] = cmadd2(u[0], a0, u[1], a1); v[3] = cmadd2(u[2], a0, u[3], a1);
}

__device__ __forceinline__ float xval(float2 a) {
  float p = a.x * a.x + a.y * a.y;
  return powf(0.8f * tanhf(52428.8f * p), 0.3f);
}

__device__ __forceinline__ void mat_from(const float* s, float2* m) {
  float st, ct, sl, cl, sp, cp, spl, cpl;
  sincosf(0.5f * s[0], &st, &ct);
  sincosf(s[2], &sl, &cl);
  sincosf(s[1], &sp, &cp);
  sincosf(s[1] + s[2], &spl, &cpl);
  m[0] = make_float2(ct, 0.f);
  m[1] = make_float2(-cl * st, -sl * st);
  m[2] = make_float2(cp * st, sp * st);
  m[3] = make_float2(cpl * ct, spl * ct);
}

// TYPE 0 = S1, 1 = S2; INIT synthesizes |0..0>; FINAL does readout.
template <int TYPE, int INIT, int FINAL>
__global__ __launch_bounds__(NT, 4) void pass_k(const float* __restrict__ u3p,
                                                const float* __restrict__ cu3p, int k,
                                                const float2* __restrict__ in,
                                                float2* __restrict__ outPsi,
                                                float* __restrict__ accum,
                                                float* __restrict__ out) {
  __shared__ float4 A4[1024], B4[1024];  // rotation double-buffer (16 KB each)
  __shared__ float2 M[168];              // MU: U3 q at [4q]; MC=M+80: W1 link c at [4c]
  __shared__ float red[8];
  unsigned t = threadIdx.x, b = blockIdx.x;

  // start psi loads first so they overlap the sincos below
  float2 v[4];
  if (INIT) {
    v[0] = v[1] = v[2] = v[3] = make_float2(0.f, 0.f);
    if (b == 0 && t == 0) { v[0] = make_float2(1.f, 0.f); *accum = 0.f; }
  } else {
    const float4* in4 = (const float4*)in + ((size_t)b << 10) + 2u * t;
    float4 f0 = in4[0], f1 = in4[1];
    v[0] = make_float2(f0.x, f0.y); v[1] = make_float2(f0.z, f0.w);
    v[2] = make_float2(f1.x, f1.y); v[3] = make_float2(f1.z, f1.w);
  }

  // this layer's matrices: MU[q] = U3(q); MC[c] = u_c * U3(c+1) (fused W1),
  // except MC[19] = raw u_19 (its target q0's U3 was already applied in S1).
  float2* MU = M;
  float2* MC = M + 80;
  if (t < 20) {
    mat_from(u3p + (k * 20 + t) * 3, MU + 4 * t);
  } else if (t >= 64 && t < 84) {
    unsigned c = t - 64;
    float2 u[4];
    mat_from(cu3p + (k * 20 + c) * 3, u);
    if (c == 19) {
      MC[76] = u[0]; MC[77] = u[1]; MC[78] = u[2]; MC[79] = u[3];
    } else {
      float2 ut[4];
      mat_from(u3p + (k * 20 + c + 1) * 3, ut);
      MC[4 * c + 0] = cadd(cmul(u[0], ut[0]), cmul(u[1], ut[2]));
      MC[4 * c + 1] = cadd(cmul(u[0], ut[1]), cmul(u[1], ut[3]));
      MC[4 * c + 2] = cadd(cmul(u[2], ut[0]), cmul(u[3], ut[2]));
      MC[4 * c + 3] = cadd(cmul(u[2], ut[1]), cmul(u[3], ut[3]));
    }
  }
  __syncthreads();

  // 10 phases; window = tile bits (p, p+1); rotate-by-1 between phases.
#pragma unroll
  for (int p = 0; p < 10; ++p) {
    if (TYPE == 0) {
      if (p == 0) applyU3b0(v, MU);             // U0 standalone
      applyF(v, MU + 4 * (p + 1), MC + 4 * p);  // U_{p+1} + C_{p,p+1}
    } else {
      if (p < 9) applyF(v, MU + 4 * (11 + p), MC + 4 * (10 + p));
      else       applyC(v, MC + 4 * 19);        // raw C(19,0)
    }
    if (p < 9) {
      // rotate-by-1: L' = (L>>1)|((L&1)<<10). Thread regs L=4t+j:
      // f4[t]=(v0,v2) [f2 2t,2t+1]; f4[t+512]=(v1,v3) [f2 2t+1024,+1025]
      float4* buf = (p & 1) ? B4 : A4;
      buf[SW(t)]        = make_float4(v[0].x, v[0].y, v[2].x, v[2].y);
      buf[SW(t + 512u)] = make_float4(v[1].x, v[1].y, v[3].x, v[3].y);
      __syncthreads();
      float4 fa = buf[SW(2u * t)], fb = buf[SW(2u * t + 1u)];
      v[0] = make_float2(fa.x, fa.y); v[1] = make_float2(fa.z, fa.w);
      v[2] = make_float2(fb.x, fb.y); v[3] = make_float2(fb.z, fb.w);
    }
  }

  // final regs: j=(tile bit9, bit10), t = tile bits 0..8.
  if (!FINAL) {
    // inter-pass layout: f4 = b + t0*2^9 + (t>>1)*2^10 + j0*2^18, pair over j1.
    float4* o4 = (float4*)outPsi;
    unsigned base = b + ((t & 1u) << 9) + ((t >> 1) << 10);
    o4[base]              = make_float4(v[0].x, v[0].y, v[2].x, v[2].y);
    o4[base + (1u << 18)] = make_float4(v[1].x, v[1].y, v[3].x, v[3].y);
  } else {
    // S2(2) end: j0=q19, j1=q0, t=(q10..q18), b=(q1..q9).
    // R = j0 + 2*rev9(t) + 1024*rev9(b) + 2^19*j1
    float xv0 = xval(v[0]), xv1 = xval(v[1]), xv2 = xval(v[2]), xv3 = xval(v[3]);
    float s = xv0 + xv1 + xv2 + xv3;
    float2* o2 = (float2*)out;
    unsigned rt = __brev(t) >> 23, rb = __brev(b) >> 23;
    unsigned base = rt + (rb << 9);
    o2[base] = make_float2(xv0, xv1);
    o2[base + (1u << 18)] = make_float2(xv2, xv3);
#pragma unroll
    for (int o = 32; o > 0; o >>= 1) s += __shfl_down(s, o);
    if ((t & 63u) == 0) red[t >> 6] = s;
    __syncthreads();
    if (t == 0) {
      float tot = 0.f;
#pragma unroll
      for (int i = 0; i < 8; i++) tot += red[i];
      atomicAdd(accum, tot);
    }
  }
}

__global__ void fin_k(float* __restrict__ out, const float* __restrict__ accum) {
  unsigned i = blockIdx.x * blockDim.x + threadIdx.x;
  float mean = *accum * (1.f / 1048576.f);
  float4* o4 = (float4*)out;
  float4 x = o4[i];
  x.x -= mean; x.y -= mean; x.z -= mean; x.w -= mean;
  o4[i] = x;
}

extern "C" void kernel_launch(void* const* d_in, const int* in_sizes, int n_in,
                              void* d_out, int out_size, void* d_ws, size_t ws_size,
                              hipStream_t stream) {
  const float* u3p = (const float*)d_in[0];
  const float* cu3p = (const float*)d_in[1];
  float* out = (float*)d_out;

  char* ws = (char*)d_ws;
  float2* psiA = (float2*)ws;                              // 8 MB
  float2* psiB = (float2*)(ws + (size_t)8 * 1024 * 1024);  // 8 MB
  float* accum = (float*)(ws + (size_t)16 * 1024 * 1024);

  pass_k<0, 1, 0><<<NB, NT, 0, stream>>>(u3p, cu3p, 0, nullptr, psiB, accum, out);
  pass_k<1, 0, 0><<<NB, NT, 0, stream>>>(u3p, cu3p, 0, psiB, psiA, accum, out);
  pass_k<0, 0, 0><<<NB, NT, 0, stream>>>(u3p, cu3p, 1, psiA, psiB, accum, out);
  pass_k<1, 0, 0><<<NB, NT, 0, stream>>>(u3p, cu3p, 1, psiB, psiA, accum, out);
  pass_k<0, 0, 0><<<NB, NT, 0, stream>>>(u3p, cu3p, 2, psiA, psiB, accum, out);
  pass_k<1, 0, 1><<<NB, NT, 0, stream>>>(u3p, cu3p, 2, psiB, nullptr, accum, out);
  fin_k<<<1024, 256, 0, stream>>>(out, accum);
}